// Round 4
// baseline (472.468 us; speedup 1.0000x reference)
//
#include <hip/hip_runtime.h>
#include <hip/hip_bf16.h>

#define T_STEPS 256
#define B_COLS  65536
#define GAMMA_F 0.99f
#define CHUNK   32
#define NCHUNK  8                 // T_STEPS / CHUNK
#define COLS_PB 32                // columns per block
// block = NCHUNK * COLS_PB = 256 threads

// Backward affine scan, chunk-parallel formulation.
// Per step (descending i): ret_i = acc*d'_i + r'_i ; acc = l_i ? tv_i : ret_i
// acc-update is affine => each thread runs its 32-step chunk SYMBOLICALLY in
// the incoming accumulator alpha: ret_i = p_i*alpha + q_i, chunk map (A,B).
// 32-thread LDS scan composes the 8 chunk maps per column -> alpha per chunk,
// then outputs are emitted from registers. Single pass over HBM, 8x threads
// vs 1-thread-per-column (16 waves/CU instead of 4) -> MLP via occupancy,
// not compiler scheduling (which rounds 1-3 proved unwinnable).

__global__ __launch_bounds__(256, 4) void td_loss_kernel(
    const float* __restrict__ reward,
    const float* __restrict__ discount,
    const float* __restrict__ value,
    const float* __restrict__ target_value,
    const int*   __restrict__ step_type,
    const int*   __restrict__ rollout_b,
    const int*   __restrict__ train_b,
    float*       __restrict__ out)
{
    const int col   = threadIdx.x & (COLS_PB - 1);
    const int chunk = threadIdx.x >> 5;           // 0..7
    const unsigned colg = blockIdx.x * COLS_PB + col;

    const int  hi  = chunk * CHUNK + (CHUNK - 1); // top step of this chunk
    const bool top = (hi == T_STEPS - 1);         // chunk 7: pseudo-init step

    float p[CHUNK], q[CHUNK], vv[CHUNK];
    float P = 1.0f, Q = 0.0f;                     // acc_sym = P*alpha + Q

    // ---- pass 1: symbolic scan over the chunk (descending i) ----
    #pragma unroll
    for (int j = 0; j < CHUNK; ++j) {
        const int i  = hi - j;
        // d'/r' live at row i+1; clamp for the pseudo-step i==255 (unused).
        const int i1 = (j == 0 && top) ? i : (i + 1);
        const unsigned idx  = (unsigned)i  * B_COLS + colg;
        const unsigned idx1 = (unsigned)i1 * B_COLS + colg;

        const float dp = discount[idx1] * GAMMA_F;
        const float rp = reward[idx1];
        const float tv = target_value[idx];
        vv[j] = value[idx];
        const int st = step_type[idx];
        const int rb = rollout_b[idx];
        const int tb = train_b[idx];

        bool l = (st == 2) | (rb != 0) | (tb != 0);
        if (j == 0) l = l | top;   // i==255: force acc := tv[255]

        p[j] = P * dp;
        q[j] = fmaf(Q, dp, rp);
        P = l ? 0.0f : p[j];
        Q = l ? tv   : q[j];
    }

    // ---- cross-chunk scan in LDS ----
    __shared__ float sA [NCHUNK][COLS_PB];
    __shared__ float sB [NCHUNK][COLS_PB];
    __shared__ float sAl[NCHUNK][COLS_PB];
    sA[chunk][col] = P;
    sB[chunk][col] = Q;
    __syncthreads();
    if (threadIdx.x < COLS_PB) {
        const int c = threadIdx.x;
        float alpha = 0.0f;                        // alpha_7 unused (P killed)
        #pragma unroll
        for (int k = NCHUNK - 1; k >= 0; --k) {
            sAl[k][c] = alpha;
            alpha = fmaf(sA[k][c], alpha, sB[k][c]);
        }
    }
    __syncthreads();
    const float alpha = sAl[chunk][col];

    // ---- pass 2: emit outputs from registers ----
    #pragma unroll
    for (int j = 0; j < CHUNK; ++j) {
        const int i = hi - j;
        const unsigned idx = (unsigned)i * B_COLS + colg;
        const float ret  = fmaf(p[j], alpha, q[j]);
        const float diff = ret - vv[j];
        float o = diff * diff;
        if (j == 0 && top) o = 0.0f;               // loss[T-1] = 0
        out[idx] = o;
    }
}

extern "C" void kernel_launch(void* const* d_in, const int* in_sizes, int n_in,
                              void* d_out, int out_size, void* d_ws, size_t ws_size,
                              hipStream_t stream) {
    const float* reward       = (const float*)d_in[0];
    const float* discount     = (const float*)d_in[1];
    const float* value        = (const float*)d_in[2];
    const float* target_value = (const float*)d_in[3];
    const int*   step_type    = (const int*)d_in[4];
    const int*   rollout_b    = (const int*)d_in[5];
    const int*   train_b      = (const int*)d_in[6];
    float*       out          = (float*)d_out;

    const int block = NCHUNK * COLS_PB;           // 256
    const int grid  = B_COLS / COLS_PB;           // 2048 blocks
    td_loss_kernel<<<grid, block, 0, stream>>>(
        reward, discount, value, target_value, step_type, rollout_b, train_b, out);
}